// Round 13
// baseline (141.113 us; speedup 1.0000x reference)
//
#include <hip/hip_runtime.h>
#include <hip/hip_bf16.h>
#include <cstddef>

#define N_NODES 50000
#define M_NBR   12
#define C_CH    128
#define F_DIM   64
#define E_EDGES (N_NODES * M_NBR)
#define NSUP    18750                // 600000 / 32 edges per super-tile
#define SUP_PER_WAVE 4
#define NBLK_A  1172                 // ceil(18750 / (4 waves * 4 sup))
#define NBLK_Y  782                  // ceil(50000 / 64)
#define NBLK_G  1563                 // 8 nodes/wave, 4 waves => 32 nodes/block

// 1 / (sqrt(4*pi) * sqrt(C) * M)
constexpr float SCALE_CE =
    (float)(1.0 / (3.5449077018110318 * 11.313708498984761 * 12.0));

typedef __bf16 bf16x8 __attribute__((ext_vector_type(8)));
typedef float  f32x4  __attribute__((ext_vector_type(4)));

// fast softplus: ln(1+e^x) = max(x,0) + ln2*log2(1 + 2^(-|x|*log2e))
__device__ __forceinline__ float softplus_f(float x) {
    const float t = __builtin_amdgcn_exp2f(-fabsf(x) * 1.44269504f);
    return fmaxf(x, 0.0f) + 0.69314718f * __builtin_amdgcn_logf(1.0f + t);
}

__device__ __forceinline__ float bfhi_to_f(unsigned int p) {   // high 16 bits
    return __uint_as_float(p & 0xffff0000u);
}
__device__ __forceinline__ float bflo_to_f(unsigned int p) {   // low 16 bits
    return __uint_as_float(p << 16);
}

// kFront: blocks [0, NBLK_A)  = edge-MLP -> ce (w1 frags built from LDS-staged w1)
//         blocks [NBLK_A, +NBLK_Y) = y = atom_fea @ tp_w (tp_w staged per K-slice)
__global__ __launch_bounds__(256) void kFront(
    const float* __restrict__ nbr_fea,
    const float* __restrict__ w1,
    const float* __restrict__ b1,
    const float* __restrict__ w2,
    const float* __restrict__ b2,
    const float* __restrict__ atom_fea,
    const float* __restrict__ tp_w,
    float* __restrict__ ce,
    __bf16* __restrict__ y)
{
    // kA1: stage w1 16KB (once), then 4 waves x bf16[32][72] = 18432 B
    // kY : stage tp_w K-slice 16KB, then yl bf16[64][136] = 17408 B
    __shared__ __align__(16) unsigned char smem[18432];
    const int tid   = threadIdx.x;
    const int lane  = tid & 63;
    const int wid   = tid >> 6;
    const int col16 = lane & 15;
    const int kgrp  = lane >> 4;

    if (blockIdx.x < NBLK_A) {
        // ---------------- edge-MLP half ----------------
        // stage w1 (coalesced) and build B-fragments from LDS
        float* WS = (float*)smem;
        #pragma unroll
        for (int i = 0; i < 4; ++i) {
            const int idx = (tid + i * 256) * 4;
            *(float4*)&WS[idx] = *(const float4*)&w1[idx];
        }
        __syncthreads();
        bf16x8 bfrag[4][2];
        #pragma unroll
        for (int n = 0; n < 4; ++n)
            #pragma unroll
            for (int ks = 0; ks < 2; ++ks)
                #pragma unroll
                for (int j = 0; j < 8; ++j)
                    bfrag[n][ks][j] =
                        (__bf16)WS[(ks * 32 + kgrp * 8 + j) * F_DIM + 16 * n + col16];
        __syncthreads();   // smem reused as per-wave tile buffers below

        float b1v[4], w2v[4];
        #pragma unroll
        for (int n = 0; n < 4; ++n) {
            b1v[n] = b1[16 * n + col16];
            w2v[n] = w2[(16 * n + col16) * 9];   // w2[:,0]
        }
        const float b2_0 = b2[0];

        __bf16* S = (__bf16*)(smem + (size_t)wid * 4608);   // [32][72] bf16
        const int sup_base = (blockIdx.x * 4 + wid) * SUP_PER_WAVE;

        float4 pre[8];
        if (sup_base < NSUP) {
            const float* g = nbr_fea + (size_t)sup_base * 32 * F_DIM;
            #pragma unroll
            for (int i = 0; i < 8; ++i)
                pre[i] = *(const float4*)(g + (size_t)(i * 64 + lane) * 4);
        }

        #pragma unroll
        for (int st = 0; st < SUP_PER_WAVE; ++st) {
            const int sup = sup_base + st;
            if (sup >= NSUP) break;

            // commit staged tile to LDS as bf16 (8 x ds_write_b64)
            #pragma unroll
            for (int i = 0; i < 8; ++i) {
                const int gi16 = i * 64 + lane;
                const int row = gi16 >> 4, u = gi16 & 15;
                union { __bf16 h[4]; uint2 u2; } pk;
                pk.h[0] = (__bf16)pre[i].x; pk.h[1] = (__bf16)pre[i].y;
                pk.h[2] = (__bf16)pre[i].z; pk.h[3] = (__bf16)pre[i].w;
                *(uint2*)&S[row * 72 + u * 4] = pk.u2;
            }
            // prefetch next super-tile (lands under the compute below)
            if (st + 1 < SUP_PER_WAVE && sup + 1 < NSUP) {
                const float* g = nbr_fea + (size_t)(sup + 1) * 32 * F_DIM;
                #pragma unroll
                for (int i = 0; i < 8; ++i)
                    pre[i] = *(const float4*)(g + (size_t)(i * 64 + lane) * 4);
            }

            const long e0 = (long)sup * 32;
            #pragma unroll
            for (int t = 0; t < 2; ++t) {
                bf16x8 afrag[2];
                #pragma unroll
                for (int ks = 0; ks < 2; ++ks)
                    afrag[ks] = *(const bf16x8*)
                        &S[(t * 16 + col16) * 72 + ks * 32 + kgrp * 8];

                f32x4 acc[4];
                #pragma unroll
                for (int n = 0; n < 4; ++n) acc[n] = (f32x4){0.f, 0.f, 0.f, 0.f};
                #pragma unroll
                for (int ks = 0; ks < 2; ++ks)
                    #pragma unroll
                    for (int n = 0; n < 4; ++n)
                        acc[n] = __builtin_amdgcn_mfma_f32_16x16x32_bf16(
                            afrag[ks], bfrag[n][ks], acc[n], 0, 0, 0);

                // D: col = lane&15 (+16n), row(edge) = kgrp*4 + r
                float partial[4] = {0.f, 0.f, 0.f, 0.f};
                #pragma unroll
                for (int n = 0; n < 4; ++n)
                    #pragma unroll
                    for (int r = 0; r < 4; ++r) {
                        const float h = acc[n][r] + b1v[n];
                        partial[r] = fmaf(softplus_f(h), w2v[n], partial[r]);
                    }
                #pragma unroll
                for (int r = 0; r < 4; ++r) {
                    #pragma unroll
                    for (int off = 1; off <= 8; off <<= 1)
                        partial[r] += __shfl_xor(partial[r], off);
                }
                if (col16 == 0) {
                    const long et = e0 + t * 16;
                    #pragma unroll
                    for (int r = 0; r < 4; ++r)
                        ce[et + kgrp * 4 + r] = (partial[r] + b2_0) * SCALE_CE;
                }
            }
        }
    } else {
        // ---------------- y = atom @ tp_w half ----------------
        const int blk  = blockIdx.x - NBLK_A;
        const int row  = blk * 64 + wid * 16 + col16;
        const int rowc = row < N_NODES ? row : N_NODES - 1;
        const float* ap = atom_fea + (size_t)rowc * C_CH + kgrp * 8;

        bf16x8 afrag[4];
        #pragma unroll
        for (int ks = 0; ks < 4; ++ks) {
            float4 f0 = *(const float4*)(ap + ks * 32);
            float4 f1 = *(const float4*)(ap + ks * 32 + 4);
            afrag[ks][0] = (__bf16)f0.x; afrag[ks][1] = (__bf16)f0.y;
            afrag[ks][2] = (__bf16)f0.z; afrag[ks][3] = (__bf16)f0.w;
            afrag[ks][4] = (__bf16)f1.x; afrag[ks][5] = (__bf16)f1.y;
            afrag[ks][6] = (__bf16)f1.z; afrag[ks][7] = (__bf16)f1.w;
        }

        // accumulate over K-slices; stage each tp_w slice (16KB) in LDS
        float* TS = (float*)smem;
        f32x4 acc[8];
        #pragma unroll
        for (int n = 0; n < 8; ++n) acc[n] = (f32x4){0.f, 0.f, 0.f, 0.f};

        #pragma unroll
        for (int ks = 0; ks < 4; ++ks) {
            const float* slice = tp_w + (size_t)ks * 32 * C_CH;
            #pragma unroll
            for (int i = 0; i < 4; ++i) {
                const int idx = (tid + i * 256) * 4;
                *(float4*)&TS[idx] = *(const float4*)&slice[idx];
            }
            __syncthreads();
            #pragma unroll
            for (int n = 0; n < 8; ++n) {
                bf16x8 bf;
                #pragma unroll
                for (int j = 0; j < 8; ++j)
                    bf[j] = (__bf16)TS[(kgrp * 8 + j) * C_CH + 16 * n + col16];
                acc[n] = __builtin_amdgcn_mfma_f32_16x16x32_bf16(
                    afrag[ks], bf, acc[n], 0, 0, 0);
            }
            __syncthreads();   // before restaging / reusing smem
        }

        __bf16* yl = (__bf16*)smem;              // [64][136]
        #pragma unroll
        for (int n = 0; n < 8; ++n)
            #pragma unroll
            for (int r = 0; r < 4; ++r)
                yl[(wid * 16 + kgrp * 4 + r) * 136 + 16 * n + col16] = (__bf16)acc[n][r];
        __syncthreads();

        #pragma unroll
        for (int it = 0; it < 4; ++it) {
            const int e  = it * 2048 + tid * 8;
            const int rw = e >> 7, cl = e & 127;
            const int grow = blk * 64 + rw;
            if (grow < N_NODES) {
                bf16x8 v = *(const bf16x8*)&yl[rw * 136 + cl];
                *(bf16x8*)&y[(size_t)grow * C_CH + cl] = v;
            }
        }
    }
}

// Kernel G: 8 nodes/wave (2x TLP vs R12), dependent gather chain; x packed bf16x2.
__global__ __launch_bounds__(256, 6) void kG(
    const float* __restrict__ atom_fea,
    const __bf16* __restrict__ y,
    const int*   __restrict__ nbr_idx,
    const float* __restrict__ ce,
    unsigned int* __restrict__ xb,     // [N_NODES*64] packed bf16x2
    float* __restrict__ psum,
    float* __restrict__ psumsq)
{
    __shared__ float4 red[4][64];
    const int tid  = threadIdx.x;
    const int lane = tid & 63;
    const int wid  = tid >> 6;
    const int blk  = blockIdx.x;
    const int i0   = blk * 32 + wid * 8;

    float2 sum   = make_float2(0.f, 0.f);
    float2 sumsq = make_float2(0.f, 0.f);

    int   pidx = 0;
    float pce  = 0.f;
    if (i0 < N_NODES && lane < M_NBR) {
        pidx = nbr_idx[i0 * M_NBR + lane];
        pce  = ce[i0 * M_NBR + lane];
    }

    for (int t = 0; t < 8; ++t) {
        const int i = i0 + t;
        const int   cidx = pidx;
        const float cce  = pce;
        const int inext = i + 1;
        if (t < 7 && inext < N_NODES && lane < M_NBR) {
            pidx = nbr_idx[inext * M_NBR + lane];
            pce  = ce[inext * M_NBR + lane];
        }
        if (i < N_NODES) {
            float2 acc = make_float2(0.f, 0.f);
            #pragma unroll
            for (int m = 0; m < M_NBR; ++m) {
                const int   src = __shfl(cidx, m);
                const float c   = __shfl(cce, m);
                const unsigned int p =
                    *(const unsigned int*)(y + (size_t)src * C_CH + lane * 2);
                acc.x = fmaf(c, bflo_to_f(p), acc.x);
                acc.y = fmaf(c, bfhi_to_f(p), acc.y);
            }
            const float2 a = *(const float2*)(atom_fea + (size_t)i * C_CH + lane * 2);
            const float2 xv = make_float2(a.x + acc.x, a.y + acc.y);
            union { __bf16 h[2]; unsigned int u; } pk;
            pk.h[0] = (__bf16)xv.x;
            pk.h[1] = (__bf16)xv.y;
            xb[(size_t)i * 64 + lane] = pk.u;
            sum.x += xv.x; sum.y += xv.y;
            sumsq.x += xv.x * xv.x; sumsq.y += xv.y * xv.y;
        }
    }

    red[wid][lane] = make_float4(sum.x, sum.y, sumsq.x, sumsq.y);
    __syncthreads();
    if (tid < 128) {
        const int l = tid >> 1, comp = tid & 1;
        float s = 0.f, q = 0.f;
        #pragma unroll
        for (int w = 0; w < 4; ++w) {
            const float4 v = red[w][l];
            s += comp ? v.y : v.x;
            q += comp ? v.w : v.z;
        }
        psum[blk * 128 + tid]   = s;
        psumsq[blk * 128 + tid] = q;
    }
}

// Kernel C1: finalize mean / inv-std. 1024 threads: 8 row-groups x 128 ch.
__global__ __launch_bounds__(1024) void kC1(
    const float* __restrict__ psum,
    const float* __restrict__ psumsq,
    float* __restrict__ mean_o,
    float* __restrict__ istd_o,
    int nblocks)
{
    __shared__ float red[2][8][128];
    const int t = threadIdx.x;
    const int c = t & 127;
    const int grp = t >> 7;
    float s = 0.f, ss = 0.f;
    for (int b = grp; b < nblocks; b += 8) {
        s  += psum[b * 128 + c];
        ss += psumsq[b * 128 + c];
    }
    red[0][grp][c] = s;
    red[1][grp][c] = ss;
    __syncthreads();
    if (t < 128) {
        float S = 0.f, SS = 0.f;
        #pragma unroll
        for (int k = 0; k < 8; ++k) { S += red[0][k][t]; SS += red[1][k][t]; }
        const float m   = S / (float)N_NODES;
        const float var = SS / (float)N_NODES - m * m;
        mean_o[t] = m;
        istd_o[t] = rsqrtf(var + 1e-5f);
    }
}

// Kernel C2: out = softplus(gamma * (x - mean) * istd + beta); x read as bf16.
__global__ __launch_bounds__(256) void kC2(
    const unsigned int* __restrict__ xb,
    float* __restrict__ out,
    const float* __restrict__ mean_i,
    const float* __restrict__ istd_i,
    const float* __restrict__ gamma,
    const float* __restrict__ beta)
{
    __shared__ float sm[128], si[128], sg[128], sb[128];
    const int tid = threadIdx.x;
    if (tid < 128) {
        sm[tid] = mean_i[tid];
        si[tid] = istd_i[tid];
        sg[tid] = gamma[tid];
        sb[tid] = beta[tid];
    }
    __syncthreads();
    const size_t tix = (size_t)blockIdx.x * 256 + tid;   // 4 channels per thread
    const uint2 v = *(const uint2*)&xb[tix * 2];
    const int c0 = (int)(tix & 31) * 4;
    float r[4] = {bflo_to_f(v.x), bfhi_to_f(v.x), bflo_to_f(v.y), bfhi_to_f(v.y)};
    float4 o;
    #pragma unroll
    for (int t = 0; t < 4; ++t) {
        const int cc = c0 + t;
        const float xn = (r[t] - sm[cc]) * si[cc];
        r[t] = softplus_f(fmaf(sg[cc], xn, sb[cc]));
    }
    o.x = r[0]; o.y = r[1]; o.z = r[2]; o.w = r[3];
    *(float4*)&out[tix * 4] = o;
}

extern "C" void kernel_launch(void* const* d_in, const int* in_sizes, int n_in,
                              void* d_out, int out_size, void* d_ws, size_t ws_size,
                              hipStream_t stream)
{
    const float* atom_fea = (const float*)d_in[0];
    const float* nbr_fea  = (const float*)d_in[1];
    const int*   nbr_idx  = (const int*)d_in[2];
    // d_in[3] = pos : unused (only the l=0 SH component survives; it is constant)
    const float* w1       = (const float*)d_in[4];
    const float* b1       = (const float*)d_in[5];
    const float* w2       = (const float*)d_in[6];
    const float* b2       = (const float*)d_in[7];
    const float* tp_w     = (const float*)d_in[8];
    const float* bn_gamma = (const float*)d_in[9];
    const float* bn_beta  = (const float*)d_in[10];

    float* out = (float*)d_out;
    float* ws  = (float*)d_ws;

    float* ce      = ws;                                   // [600000]
    float* psum    = ce + E_EDGES;                         // [1563*128]
    float* psumsq  = psum + (size_t)NBLK_G * 128;          // [1563*128]
    float* mean_b  = psumsq + (size_t)NBLK_G * 128;        // [128]
    float* istd_b  = mean_b + 128;                         // [128]
    __bf16* ybuf   = (__bf16*)(istd_b + 128);              // [6400000]
    unsigned int* xbuf = (unsigned int*)(ybuf + 6400000);  // [3200000]

    kFront<<<NBLK_A + NBLK_Y, 256, 0, stream>>>(
        nbr_fea, w1, b1, w2, b2, atom_fea, tp_w, ce, ybuf);
    kG<<<NBLK_G, 256, 0, stream>>>(atom_fea, ybuf, nbr_idx, ce,
                                   xbuf, psum, psumsq);
    kC1<<<1, 1024, 0, stream>>>(psum, psumsq, mean_b, istd_b, NBLK_G);
    const int nC2 = (N_NODES * C_CH / 4) / 256;            // 6250 blocks
    kC2<<<nC2, 256, 0, stream>>>(xbuf, out, mean_b, istd_b, bn_gamma, bn_beta);
}

// Round 14
// 109.906 us; speedup vs baseline: 1.2839x; 1.2839x over previous
//
#include <hip/hip_runtime.h>
#include <hip/hip_bf16.h>
#include <cstddef>

#define N_NODES 50000
#define M_NBR   12
#define C_CH    128
#define F_DIM   64
#define E_EDGES (N_NODES * M_NBR)
#define NSUP    18750                // 600000 / 32 edges per super-tile
#define SUP_PER_WAVE 4
#define NBLK_A  1172                 // ceil(18750 / (4 waves * 4 sup))
#define NBLK_Y  782                  // ceil(50000 / 64)
#define NBLK_G  782                  // 16 nodes/wave, 4 waves

// 1 / (sqrt(4*pi) * sqrt(C) * M)
constexpr float SCALE_CE =
    (float)(1.0 / (3.5449077018110318 * 11.313708498984761 * 12.0));

typedef __bf16 bf16x8 __attribute__((ext_vector_type(8)));
typedef float  f32x4  __attribute__((ext_vector_type(4)));

// fast softplus: ln(1+e^x) = max(x,0) + ln2*log2(1 + 2^(-|x|*log2e))
__device__ __forceinline__ float softplus_f(float x) {
    const float t = __builtin_amdgcn_exp2f(-fabsf(x) * 1.44269504f);
    return fmaxf(x, 0.0f) + 0.69314718f * __builtin_amdgcn_logf(1.0f + t);
}

__device__ __forceinline__ float bfhi_to_f(unsigned int p) {   // high 16 bits
    return __uint_as_float(p & 0xffff0000u);
}
__device__ __forceinline__ float bflo_to_f(unsigned int p) {   // low 16 bits
    return __uint_as_float(p << 16);
}

// Pre-kernel: build bf16 MFMA B-fragments for w1 (block 0) and tp_w (blocks 1-4).
// NOTE (R6/R13 lesson): per-block self-build of these fragments costs ~35 us
// (stride-256B LDS bank conflicts + VGPR pressure). Prebuilding here costs ~2 us.
__global__ __launch_bounds__(512) void kW(
    const float* __restrict__ w1,
    const float* __restrict__ tp_w,
    __bf16* __restrict__ fragW1,
    __bf16* __restrict__ fragTP)
{
    const int t = threadIdx.x;
    if (blockIdx.x == 0) {
        const int lane = t & 63;
        const int f = t >> 6;                 // n*2+ks
        const int n = f >> 1, ks = f & 1;
        const int col16 = lane & 15, kgrp = lane >> 4;
        bf16x8 v;
        #pragma unroll
        for (int j = 0; j < 8; ++j)
            v[j] = (__bf16)w1[(ks * 32 + kgrp * 8 + j) * F_DIM + 16 * n + col16];
        *(bf16x8*)&fragW1[(size_t)t * 8] = v;
    } else {
        const int fid = (blockIdx.x - 1) * 512 + t;   // 0..2047
        const int lane = fid & 63;
        const int f = fid >> 6;               // n*4+ks
        const int n = f >> 2, ks = f & 3;
        const int col16 = lane & 15, kgrp = lane >> 4;
        bf16x8 v;
        #pragma unroll
        for (int j = 0; j < 8; ++j)
            v[j] = (__bf16)tp_w[(ks * 32 + kgrp * 8 + j) * C_CH + 16 * n + col16];
        *(bf16x8*)&fragTP[(size_t)fid * 8] = v;
    }
}

// kFront: blocks [0, NBLK_A)  = edge-MLP -> ce, reg-prefetch pipelined staging
//         blocks [NBLK_A, +NBLK_Y) = y = atom_fea @ tp_w (bf16 out)
__global__ __launch_bounds__(256) void kFront(
    const float* __restrict__ nbr_fea,
    const __bf16* __restrict__ fragW1,
    const float* __restrict__ b1,
    const float* __restrict__ w2,
    const float* __restrict__ b2,
    const float* __restrict__ atom_fea,
    const __bf16* __restrict__ fragTP,
    float* __restrict__ ce,
    __bf16* __restrict__ y)
{
    // kA1: 4 waves x bf16[32 rows][72] (144B stride, 16B-aligned) = 18432 B
    // kY : bf16[64][136] = 17408 B
    __shared__ __align__(16) unsigned char smem[18432];
    const int tid   = threadIdx.x;
    const int lane  = tid & 63;
    const int wid   = tid >> 6;
    const int col16 = lane & 15;
    const int kgrp  = lane >> 4;

    if (blockIdx.x < NBLK_A) {
        // ---------------- edge-MLP half ----------------
        bf16x8 bfrag[4][2];
        #pragma unroll
        for (int f = 0; f < 8; ++f)
            bfrag[f >> 1][f & 1] = *(const bf16x8*)&fragW1[((size_t)f * 64 + lane) * 8];

        float b1v[4], w2v[4];
        #pragma unroll
        for (int n = 0; n < 4; ++n) {
            b1v[n] = b1[16 * n + col16];
            w2v[n] = w2[(16 * n + col16) * 9];   // w2[:,0]
        }
        const float b2_0 = b2[0];

        __bf16* S = (__bf16*)(smem + (size_t)wid * 4608);   // [32][72] bf16
        const int sup_base = (blockIdx.x * 4 + wid) * SUP_PER_WAVE;

        float4 pre[8];
        if (sup_base < NSUP) {
            const float* g = nbr_fea + (size_t)sup_base * 32 * F_DIM;
            #pragma unroll
            for (int i = 0; i < 8; ++i)
                pre[i] = *(const float4*)(g + (size_t)(i * 64 + lane) * 4);
        }

        #pragma unroll
        for (int st = 0; st < SUP_PER_WAVE; ++st) {
            const int sup = sup_base + st;
            if (sup >= NSUP) break;

            // commit staged tile to LDS as bf16 (8 x ds_write_b64)
            #pragma unroll
            for (int i = 0; i < 8; ++i) {
                const int gi16 = i * 64 + lane;
                const int row = gi16 >> 4, u = gi16 & 15;
                union { __bf16 h[4]; uint2 u2; } pk;
                pk.h[0] = (__bf16)pre[i].x; pk.h[1] = (__bf16)pre[i].y;
                pk.h[2] = (__bf16)pre[i].z; pk.h[3] = (__bf16)pre[i].w;
                *(uint2*)&S[row * 72 + u * 4] = pk.u2;
            }
            // prefetch next super-tile (lands under the compute below)
            if (st + 1 < SUP_PER_WAVE && sup + 1 < NSUP) {
                const float* g = nbr_fea + (size_t)(sup + 1) * 32 * F_DIM;
                #pragma unroll
                for (int i = 0; i < 8; ++i)
                    pre[i] = *(const float4*)(g + (size_t)(i * 64 + lane) * 4);
            }

            const long e0 = (long)sup * 32;
            #pragma unroll
            for (int t = 0; t < 2; ++t) {
                bf16x8 afrag[2];
                #pragma unroll
                for (int ks = 0; ks < 2; ++ks)
                    afrag[ks] = *(const bf16x8*)
                        &S[(t * 16 + col16) * 72 + ks * 32 + kgrp * 8];

                f32x4 acc[4];
                #pragma unroll
                for (int n = 0; n < 4; ++n) acc[n] = (f32x4){0.f, 0.f, 0.f, 0.f};
                #pragma unroll
                for (int ks = 0; ks < 2; ++ks)
                    #pragma unroll
                    for (int n = 0; n < 4; ++n)
                        acc[n] = __builtin_amdgcn_mfma_f32_16x16x32_bf16(
                            afrag[ks], bfrag[n][ks], acc[n], 0, 0, 0);

                // D: col = lane&15 (+16n), row(edge) = kgrp*4 + r
                float partial[4] = {0.f, 0.f, 0.f, 0.f};
                #pragma unroll
                for (int n = 0; n < 4; ++n)
                    #pragma unroll
                    for (int r = 0; r < 4; ++r) {
                        const float h = acc[n][r] + b1v[n];
                        partial[r] = fmaf(softplus_f(h), w2v[n], partial[r]);
                    }
                #pragma unroll
                for (int r = 0; r < 4; ++r) {
                    #pragma unroll
                    for (int off = 1; off <= 8; off <<= 1)
                        partial[r] += __shfl_xor(partial[r], off);
                }
                if (col16 == 0) {
                    const long et = e0 + t * 16;
                    #pragma unroll
                    for (int r = 0; r < 4; ++r)
                        ce[et + kgrp * 4 + r] = (partial[r] + b2_0) * SCALE_CE;
                }
            }
        }
    } else {
        // ---------------- y = atom @ tp_w half ----------------
        __bf16* yl = (__bf16*)smem;              // [64][136]
        const int blk  = blockIdx.x - NBLK_A;
        const int row  = blk * 64 + wid * 16 + col16;
        const int rowc = row < N_NODES ? row : N_NODES - 1;
        const float* ap = atom_fea + (size_t)rowc * C_CH + kgrp * 8;

        bf16x8 afrag[4];
        #pragma unroll
        for (int ks = 0; ks < 4; ++ks) {
            float4 f0 = *(const float4*)(ap + ks * 32);
            float4 f1 = *(const float4*)(ap + ks * 32 + 4);
            afrag[ks][0] = (__bf16)f0.x; afrag[ks][1] = (__bf16)f0.y;
            afrag[ks][2] = (__bf16)f0.z; afrag[ks][3] = (__bf16)f0.w;
            afrag[ks][4] = (__bf16)f1.x; afrag[ks][5] = (__bf16)f1.y;
            afrag[ks][6] = (__bf16)f1.z; afrag[ks][7] = (__bf16)f1.w;
        }

        #pragma unroll
        for (int n = 0; n < 8; ++n) {
            f32x4 acc = (f32x4){0.f, 0.f, 0.f, 0.f};
            #pragma unroll
            for (int ks = 0; ks < 4; ++ks) {
                bf16x8 bf = *(const bf16x8*)&fragTP[((size_t)(n * 4 + ks) * 64 + lane) * 8];
                acc = __builtin_amdgcn_mfma_f32_16x16x32_bf16(afrag[ks], bf, acc, 0, 0, 0);
            }
            #pragma unroll
            for (int r = 0; r < 4; ++r)
                yl[(wid * 16 + kgrp * 4 + r) * 136 + 16 * n + col16] = (__bf16)acc[r];
        }
        __syncthreads();

        #pragma unroll
        for (int it = 0; it < 4; ++it) {
            const int e  = it * 2048 + tid * 8;
            const int rw = e >> 7, cl = e & 127;
            const int grow = blk * 64 + rw;
            if (grow < N_NODES) {
                bf16x8 v = *(const bf16x8*)&yl[rw * 136 + cl];
                *(bf16x8*)&y[(size_t)grow * C_CH + cl] = v;
            }
        }
    }
}

// Kernel G (R10/R12-proven): 16 nodes/wave, dependent gather chain; x packed bf16x2.
__global__ __launch_bounds__(256, 6) void kG(
    const float* __restrict__ atom_fea,
    const __bf16* __restrict__ y,
    const int*   __restrict__ nbr_idx,
    const float* __restrict__ ce,
    unsigned int* __restrict__ xb,     // [N_NODES*64] packed bf16x2
    float* __restrict__ psum,
    float* __restrict__ psumsq)
{
    __shared__ float4 red[4][64];
    const int tid  = threadIdx.x;
    const int lane = tid & 63;
    const int wid  = tid >> 6;
    const int blk  = blockIdx.x;
    const int i0   = blk * 64 + wid * 16;

    float2 sum   = make_float2(0.f, 0.f);
    float2 sumsq = make_float2(0.f, 0.f);

    int   pidx = 0;
    float pce  = 0.f;
    if (i0 < N_NODES && lane < M_NBR) {
        pidx = nbr_idx[i0 * M_NBR + lane];
        pce  = ce[i0 * M_NBR + lane];
    }

    for (int t = 0; t < 16; ++t) {
        const int i = i0 + t;
        const int   cidx = pidx;
        const float cce  = pce;
        const int inext = i + 1;
        if (t < 15 && inext < N_NODES && lane < M_NBR) {
            pidx = nbr_idx[inext * M_NBR + lane];
            pce  = ce[inext * M_NBR + lane];
        }
        if (i < N_NODES) {
            float2 acc = make_float2(0.f, 0.f);
            #pragma unroll
            for (int m = 0; m < M_NBR; ++m) {
                const int   src = __shfl(cidx, m);
                const float c   = __shfl(cce, m);
                const unsigned int p =
                    *(const unsigned int*)(y + (size_t)src * C_CH + lane * 2);
                acc.x = fmaf(c, bflo_to_f(p), acc.x);
                acc.y = fmaf(c, bfhi_to_f(p), acc.y);
            }
            const float2 a = *(const float2*)(atom_fea + (size_t)i * C_CH + lane * 2);
            const float2 xv = make_float2(a.x + acc.x, a.y + acc.y);
            union { __bf16 h[2]; unsigned int u; } pk;
            pk.h[0] = (__bf16)xv.x;
            pk.h[1] = (__bf16)xv.y;
            xb[(size_t)i * 64 + lane] = pk.u;
            sum.x += xv.x; sum.y += xv.y;
            sumsq.x += xv.x * xv.x; sumsq.y += xv.y * xv.y;
        }
    }

    red[wid][lane] = make_float4(sum.x, sum.y, sumsq.x, sumsq.y);
    __syncthreads();
    if (tid < 128) {
        const int l = tid >> 1, comp = tid & 1;
        float s = 0.f, q = 0.f;
        #pragma unroll
        for (int w = 0; w < 4; ++w) {
            const float4 v = red[w][l];
            s += comp ? v.y : v.x;
            q += comp ? v.w : v.z;
        }
        psum[blk * 128 + tid]   = s;
        psumsq[blk * 128 + tid] = q;
    }
}

// Kernel C1: finalize mean / inv-std. 1024 threads: 8 row-groups x 128 ch.
__global__ __launch_bounds__(1024) void kC1(
    const float* __restrict__ psum,
    const float* __restrict__ psumsq,
    float* __restrict__ mean_o,
    float* __restrict__ istd_o,
    int nblocks)
{
    __shared__ float red[2][8][128];
    const int t = threadIdx.x;
    const int c = t & 127;
    const int grp = t >> 7;
    float s = 0.f, ss = 0.f;
    for (int b = grp; b < nblocks; b += 8) {
        s  += psum[b * 128 + c];
        ss += psumsq[b * 128 + c];
    }
    red[0][grp][c] = s;
    red[1][grp][c] = ss;
    __syncthreads();
    if (t < 128) {
        float S = 0.f, SS = 0.f;
        #pragma unroll
        for (int k = 0; k < 8; ++k) { S += red[0][k][t]; SS += red[1][k][t]; }
        const float m   = S / (float)N_NODES;
        const float var = SS / (float)N_NODES - m * m;
        mean_o[t] = m;
        istd_o[t] = rsqrtf(var + 1e-5f);
    }
}

// Kernel C2: out = softplus(gamma * (x - mean) * istd + beta); x read as bf16.
__global__ __launch_bounds__(256) void kC2(
    const unsigned int* __restrict__ xb,
    float* __restrict__ out,
    const float* __restrict__ mean_i,
    const float* __restrict__ istd_i,
    const float* __restrict__ gamma,
    const float* __restrict__ beta)
{
    __shared__ float sm[128], si[128], sg[128], sb[128];
    const int tid = threadIdx.x;
    if (tid < 128) {
        sm[tid] = mean_i[tid];
        si[tid] = istd_i[tid];
        sg[tid] = gamma[tid];
        sb[tid] = beta[tid];
    }
    __syncthreads();
    const size_t tix = (size_t)blockIdx.x * 256 + tid;   // 4 channels per thread
    const uint2 v = *(const uint2*)&xb[tix * 2];
    const int c0 = (int)(tix & 31) * 4;
    float r[4] = {bflo_to_f(v.x), bfhi_to_f(v.x), bflo_to_f(v.y), bfhi_to_f(v.y)};
    float4 o;
    #pragma unroll
    for (int t = 0; t < 4; ++t) {
        const int cc = c0 + t;
        const float xn = (r[t] - sm[cc]) * si[cc];
        r[t] = softplus_f(fmaf(sg[cc], xn, sb[cc]));
    }
    o.x = r[0]; o.y = r[1]; o.z = r[2]; o.w = r[3];
    *(float4*)&out[tix * 4] = o;
}

extern "C" void kernel_launch(void* const* d_in, const int* in_sizes, int n_in,
                              void* d_out, int out_size, void* d_ws, size_t ws_size,
                              hipStream_t stream)
{
    const float* atom_fea = (const float*)d_in[0];
    const float* nbr_fea  = (const float*)d_in[1];
    const int*   nbr_idx  = (const int*)d_in[2];
    // d_in[3] = pos : unused (only the l=0 SH component survives; it is constant)
    const float* w1       = (const float*)d_in[4];
    const float* b1       = (const float*)d_in[5];
    const float* w2       = (const float*)d_in[6];
    const float* b2       = (const float*)d_in[7];
    const float* tp_w     = (const float*)d_in[8];
    const float* bn_gamma = (const float*)d_in[9];
    const float* bn_beta  = (const float*)d_in[10];

    float* out = (float*)d_out;
    float* ws  = (float*)d_ws;

    float* ce      = ws;                                   // [600000]
    float* psum    = ce + E_EDGES;                         // [782*128]
    float* psumsq  = psum + (size_t)NBLK_G * 128;          // [782*128]
    float* mean_b  = psumsq + (size_t)NBLK_G * 128;        // [128]
    float* istd_b  = mean_b + 128;                         // [128]
    __bf16* fragW1 = (__bf16*)(istd_b + 128);              // [4096]
    __bf16* fragTP = fragW1 + 4096;                        // [16384]
    __bf16* ybuf   = fragTP + 16384;                       // [6400000]
    unsigned int* xbuf = (unsigned int*)(ybuf + 6400000);  // [3200000]

    kW<<<5, 512, 0, stream>>>(w1, tp_w, fragW1, fragTP);
    kFront<<<NBLK_A + NBLK_Y, 256, 0, stream>>>(
        nbr_fea, fragW1, b1, w2, b2, atom_fea, fragTP, ce, ybuf);
    kG<<<NBLK_G, 256, 0, stream>>>(atom_fea, ybuf, nbr_idx, ce,
                                   xbuf, psum, psumsq);
    kC1<<<1, 1024, 0, stream>>>(psum, psumsq, mean_b, istd_b, NBLK_G);
    const int nC2 = (N_NODES * C_CH / 4) / 256;            // 6250 blocks
    kC2<<<nC2, 256, 0, stream>>>(xbuf, out, mean_b, istd_b, bn_gamma, bn_beta);
}